// Round 2
// baseline (790.322 us; speedup 1.0000x reference)
//
#include <hip/hip_runtime.h>

#define N_LSTM 16
#define ISZ 128
#define HSZ 128
#define BSZ 32
#define TSZ 512
#define G4H 512
#define XROW (N_LSTM * ISZ)   // 2048
#define OROW (N_LSTM * HSZ)   // 2048

typedef __attribute__((ext_vector_type(8))) short s16x8;
typedef __attribute__((ext_vector_type(4))) float f32x4;

static __device__ __forceinline__ unsigned short f2bf(float f) {
    unsigned int u = __builtin_bit_cast(unsigned int, f);
    u += 0x7fffu + ((u >> 16) & 1u);
    return (unsigned short)(u >> 16);
}

// lgkm-only barrier: syncs LDS producers/consumers WITHOUT draining vmcnt,
// so global stores / prefetch loads stay in flight across the per-step barrier.
static __device__ __forceinline__ void barrier_lgkm() {
    __builtin_amdgcn_sched_barrier(0);
    asm volatile("s_waitcnt lgkmcnt(0)" ::: "memory");
    __builtin_amdgcn_s_barrier();
    __builtin_amdgcn_sched_barrier(0);
}

// Pre-pass: convert x (fp32) to bf16 u64-packed in the EXACT order the
// recurrent kernel's staging threads consume: xbf[t][wg][tid] where
// wg = n*2+half, tid in [0,512): sr=tid>>5 (batch row), sc=(tid&31)*4 (col).
__global__ void x_to_bf16(const float* __restrict__ x,
                          unsigned long long* __restrict__ xbf) {
    const int G = blockIdx.x * 256 + threadIdx.x;   // < 512*32*512 = 8388608
    const int tid = G & 511;
    const int wg  = (G >> 9) & 31;
    const int t   = G >> 14;
    const int sr = tid >> 5;
    const int sc = (tid & 31) * 4;
    const int n  = wg >> 1;
    const int b0 = (wg & 1) * 16;
    const float* src = x + (size_t)(b0 + sr) * (TSZ * XROW) + (size_t)t * XROW + n * ISZ + sc;
    float4 v = *(const float4*)src;
    unsigned long long r = (unsigned long long)f2bf(v.x)
                         | ((unsigned long long)f2bf(v.y) << 16)
                         | ((unsigned long long)f2bf(v.z) << 32)
                         | ((unsigned long long)f2bf(v.w) << 48);
    xbf[G] = r;
}

// One workgroup = (n, batch-half of 16). 8 waves; wave w owns hidden units
// [16w, 16w+16) x all 4 gates. Weights held in registers as MFMA B-frags.
// h round-trips through LDS (bf16, double-buffered). x-projection for t+1
// computed during step t (off the recurrent critical path).
// PRE=1: x pre-converted to bf16 by x_to_bf16 (staging = load + ds_write,
// zero VALU). PRE=0: fallback in-kernel f2bf staging.
template <int PRE>
__global__ __launch_bounds__(512, 2) void widelstm_fused(
    const float* __restrict__ x, const unsigned long long* __restrict__ xbf,
    const float* __restrict__ Wih, const float* __restrict__ Whh,
    const float* __restrict__ bih, const float* __restrict__ bhh,
    float* __restrict__ out)
{
    __shared__ __align__(16) unsigned short xbuf[2][16][136];
    __shared__ __align__(16) unsigned short hbuf[2][16][136];

    const int tid = threadIdx.x;
    const int wv  = tid >> 6;        // wave 0..7 -> hid chunk
    const int ln  = tid & 63;
    const int lm  = ln & 15;         // A-row (m) / C-col
    const int lq  = ln >> 4;         // quad
    const int n    = blockIdx.x >> 1;
    const int half = blockIdx.x & 1;
    const int b0   = half * 16;

    // ---- Load weight B-fragments (once). B[k][col]: lane holds col=lm, k=lq*8+j.
    s16x8 wih[4][4], whh[4][4];
    float bias[4];
    #pragma unroll
    for (int g = 0; g < 4; ++g) {
        const int col = g * 128 + wv * 16 + lm;
        bias[g] = bih[n * G4H + col] + bhh[n * G4H + col];
        #pragma unroll
        for (int kt = 0; kt < 4; ++kt) {
            const float* pi = Wih + ((size_t)n * G4H + col) * ISZ + kt * 32 + lq * 8;
            const float* ph = Whh + ((size_t)n * G4H + col) * HSZ + kt * 32 + lq * 8;
            s16x8 a, b;
            #pragma unroll
            for (int j = 0; j < 8; ++j) {
                a[j] = (short)f2bf(pi[j]);
                b[j] = (short)f2bf(ph[j]);
            }
            wih[g][kt] = a;
            whh[g][kt] = b;
        }
    }

    // zero hbuf[0] (h(-1) = 0)
    for (int i = tid; i < 16 * 136; i += 512)
        ((unsigned short*)hbuf[0])[i] = 0;

    // ---- x staging sources
    const int sr = tid >> 5;
    const int sc = (tid & 31) * 4;
    const float* xrow = x + (size_t)(b0 + sr) * TSZ * XROW + n * ISZ + sc;   // PRE=0
    const unsigned long long* xbase = xbf + (size_t)blockIdx.x * 512 + tid;  // PRE=1

    // ---- prologue: stage x(0), compute xacc(0)
    float4 xr;   // PRE=0 prefetch reg
    uint2  xr2;  // PRE=1 prefetch reg
    if constexpr (PRE) {
        xr2 = *(const uint2*)xbase;
        *(uint2*)&xbuf[0][sr][sc] = xr2;
    } else {
        xr = *(const float4*)(xrow);
        unsigned int lo = (unsigned int)f2bf(xr.x) | ((unsigned int)f2bf(xr.y) << 16);
        unsigned int hi = (unsigned int)f2bf(xr.z) | ((unsigned int)f2bf(xr.w) << 16);
        *(uint2*)&xbuf[0][sr][sc] = make_uint2(lo, hi);
    }
    barrier_lgkm();

    f32x4 xacc[4];
    #pragma unroll
    for (int g = 0; g < 4; ++g)
        xacc[g] = (f32x4){bias[g], bias[g], bias[g], bias[g]};
    #pragma unroll
    for (int kt = 0; kt < 4; ++kt) {
        s16x8 axk = *(const s16x8*)&xbuf[0][lm][kt * 32 + lq * 8];
        #pragma unroll
        for (int g = 0; g < 4; ++g)
            xacc[g] = __builtin_amdgcn_mfma_f32_16x16x32_bf16(axk, wih[g][kt], xacc[g], 0, 0, 0);
    }

    // prefetch t = 1
    if constexpr (PRE) xr2 = *(const uint2*)(xbase + 16384);
    else               xr  = *(const float4*)(xrow + (size_t)XROW);
    const unsigned long long* xptr = xbase + 2 * 16384;   // next prefetch: t = 2

    float cprev[4] = {0.f, 0.f, 0.f, 0.f};
    float hlast[4] = {0.f, 0.f, 0.f, 0.f};
    const int ocol = n * HSZ + wv * 16 + lm;

    // strength-reduced output pointers: one per accumulator row
    float* po0 = out + (size_t)(b0 + lq * 4 + 0) * TSZ * OROW + ocol;
    float* po1 = out + (size_t)(b0 + lq * 4 + 1) * TSZ * OROW + ocol;
    float* po2 = out + (size_t)(b0 + lq * 4 + 2) * TSZ * OROW + ocol;
    float* po3 = out + (size_t)(b0 + lq * 4 + 3) * TSZ * OROW + ocol;

#define LSTM_STEP(T_, CUR_, NXT_)                                                          \
    {                                                                                      \
        const int t_ = (T_);                                                               \
        if (t_ + 1 < TSZ) {                                                                \
            if constexpr (PRE) {                                                           \
                *(uint2*)&xbuf[NXT_][sr][sc] = xr2;                                        \
            } else {                                                                       \
                unsigned int lo = (unsigned int)f2bf(xr.x) | ((unsigned int)f2bf(xr.y) << 16); \
                unsigned int hi = (unsigned int)f2bf(xr.z) | ((unsigned int)f2bf(xr.w) << 16); \
                *(uint2*)&xbuf[NXT_][sr][sc] = make_uint2(lo, hi);                         \
            }                                                                              \
        }                                                                                  \
        barrier_lgkm();  /* h(t-1) writes + x(t+1) staging now visible */                  \
        s16x8 ah0 = *(const s16x8*)&hbuf[CUR_][lm][0 * 32 + lq * 8];                       \
        s16x8 ah1 = *(const s16x8*)&hbuf[CUR_][lm][1 * 32 + lq * 8];                       \
        s16x8 ah2 = *(const s16x8*)&hbuf[CUR_][lm][2 * 32 + lq * 8];                       \
        s16x8 ah3 = *(const s16x8*)&hbuf[CUR_][lm][3 * 32 + lq * 8];                       \
        if (t_ + 2 < TSZ) {                                                                \
            if constexpr (PRE) { xr2 = *(const uint2*)xptr; xptr += 16384; }               \
            else               { xr = *(const float4*)(xrow + (size_t)(t_ + 2) * XROW); }  \
        }                                                                                  \
        f32x4 hacc[4];                                                                     \
        _Pragma("unroll")                                                                  \
        for (int g = 0; g < 4; ++g)                                                        \
            hacc[g] = __builtin_amdgcn_mfma_f32_16x16x32_bf16(ah0, whh[g][0], xacc[g], 0, 0, 0); \
        _Pragma("unroll")                                                                  \
        for (int g = 0; g < 4; ++g)                                                        \
            hacc[g] = __builtin_amdgcn_mfma_f32_16x16x32_bf16(ah1, whh[g][1], hacc[g], 0, 0, 0); \
        _Pragma("unroll")                                                                  \
        for (int g = 0; g < 4; ++g)                                                        \
            hacc[g] = __builtin_amdgcn_mfma_f32_16x16x32_bf16(ah2, whh[g][2], hacc[g], 0, 0, 0); \
        _Pragma("unroll")                                                                  \
        for (int g = 0; g < 4; ++g)                                                        \
            hacc[g] = __builtin_amdgcn_mfma_f32_16x16x32_bf16(ah3, whh[g][3], hacc[g], 0, 0, 0); \
        if (t_ + 1 < TSZ) { /* x-projection for t+1: off the critical path */              \
            _Pragma("unroll")                                                              \
            for (int g = 0; g < 4; ++g)                                                    \
                xacc[g] = (f32x4){bias[g], bias[g], bias[g], bias[g]};                     \
            _Pragma("unroll")                                                              \
            for (int kt = 0; kt < 4; ++kt) {                                               \
                s16x8 axk = *(const s16x8*)&xbuf[NXT_][lm][kt * 32 + lq * 8];              \
                _Pragma("unroll")                                                          \
                for (int g = 0; g < 4; ++g)                                                \
                    xacc[g] = __builtin_amdgcn_mfma_f32_16x16x32_bf16(axk, wih[g][kt], xacc[g], 0, 0, 0); \
            }                                                                              \
        }                                                                                  \
        /* epilogue: lane owns (row = lq*4+r, hid = 16*wv+lm).                             \
           Fused activations: sig(i)*tanh(g) = (1-eg)*rcp((1+ei)(1+eg));                   \
           sig(o)*tanh(c)   = (1-ec)*rcp((1+eo)(1+ec)). 5 exp + 3 rcp per elem. */         \
        _Pragma("unroll")                                                                  \
        for (int r = 0; r < 4; ++r) {                                                      \
            float zi = hacc[0][r], zf = hacc[1][r], zg = hacc[2][r], zo = hacc[3][r];      \
            float ei = __expf(-zi);                                                        \
            float ef = __expf(-zf);                                                        \
            float eo = __expf(-zo);                                                        \
            float zgc = fminf(fmaxf(zg, -20.f), 20.f);                                     \
            float eg  = __expf(-2.f * zgc);                                                \
            float fv  = __builtin_amdgcn_rcpf(1.f + ef);                                   \
            float ig  = (1.f - eg) * __builtin_amdgcn_rcpf((1.f + ei) * (1.f + eg));       \
            float c   = fv * cprev[r] + ig;                                                \
            cprev[r]  = c;                                                                 \
            float cc  = fminf(fmaxf(c, -20.f), 20.f);                                      \
            float ec  = __expf(-2.f * cc);                                                 \
            float hv  = (1.f - ec) * __builtin_amdgcn_rcpf((1.f + eo) * (1.f + ec));       \
            hlast[r]  = hv;                                                                \
            hbuf[NXT_][lq * 4 + r][wv * 16 + lm] = f2bf(hv);                               \
            if (r == 0) { *po0 = hv; po0 += OROW; }                                        \
            if (r == 1) { *po1 = hv; po1 += OROW; }                                        \
            if (r == 2) { *po2 = hv; po2 += OROW; }                                        \
            if (r == 3) { *po3 = hv; po3 += OROW; }                                        \
        }                                                                                  \
    }

    for (int t = 0; t < TSZ; t += 2) {
        LSTM_STEP(t, 0, 1);
        LSTM_STEP(t + 1, 1, 0);
    }
#undef LSTM_STEP

    // finals: h_n, c_n  [1, B, N*H] each
    const size_t hn_off = (size_t)BSZ * TSZ * OROW;
    const size_t cn_off = hn_off + (size_t)BSZ * OROW;
    #pragma unroll
    for (int r = 0; r < 4; ++r) {
        const int row = lq * 4 + r;
        const size_t idx = (size_t)(b0 + row) * OROW + ocol;
        out[hn_off + idx] = hlast[r];
        out[cn_off + idx] = cprev[r];
    }
}

extern "C" void kernel_launch(void* const* d_in, const int* in_sizes, int n_in,
                              void* d_out, int out_size, void* d_ws, size_t ws_size,
                              hipStream_t stream) {
    const float* x   = (const float*)d_in[0];
    const float* Wih = (const float*)d_in[1];
    const float* Whh = (const float*)d_in[2];
    const float* bih = (const float*)d_in[3];
    const float* bhh = (const float*)d_in[4];
    float* out = (float*)d_out;

    const size_t need = (size_t)TSZ * 32 * 512 * 8;   // 64 MiB
    if (d_ws != nullptr && ws_size >= need) {
        unsigned long long* xbf = (unsigned long long*)d_ws;
        x_to_bf16<<<dim3(32768), dim3(256), 0, stream>>>(x, xbf);
        widelstm_fused<1><<<dim3(32), dim3(512), 0, stream>>>(x, xbf, Wih, Whh, bih, bhh, out);
    } else {
        widelstm_fused<0><<<dim3(32), dim3(512), 0, stream>>>(x, nullptr, Wih, Whh, bih, bhh, out);
    }
}

// Round 3
// 748.539 us; speedup vs baseline: 1.0558x; 1.0558x over previous
//
#include <hip/hip_runtime.h>

#define N_LSTM 16
#define ISZ 128
#define HSZ 128
#define BSZ 32
#define TSZ 512
#define G4H 512
#define XROW (N_LSTM * ISZ)   // 2048
#define OROW (N_LSTM * HSZ)   // 2048

typedef __attribute__((ext_vector_type(8))) short s16x8;
typedef __attribute__((ext_vector_type(4))) float f32x4;

#define LOG2E 1.4426950408889634f

static __device__ __forceinline__ unsigned short f2bf(float f) {
    unsigned int u = __builtin_bit_cast(unsigned int, f);
    u += 0x7fffu + ((u >> 16) & 1u);
    return (unsigned short)(u >> 16);
}

// raw v_exp_f32: D = 2^x
static __device__ __forceinline__ float fexp2(float x) {
#if __has_builtin(__builtin_amdgcn_exp2f)
    return __builtin_amdgcn_exp2f(x);
#else
    return __expf(x * 0.6931471805599453f);   // correct fallback
#endif
}

// lgkm-only barrier: syncs LDS producers/consumers WITHOUT draining vmcnt,
// so global stores / prefetch loads stay in flight across the per-step barrier.
static __device__ __forceinline__ void barrier_lgkm() {
    __builtin_amdgcn_sched_barrier(0);
    asm volatile("s_waitcnt lgkmcnt(0)" ::: "memory");
    __builtin_amdgcn_s_barrier();
    __builtin_amdgcn_sched_barrier(0);
}

// Pre-pass: emit x as bf16 MFMA A-FRAGMENTS in the exact order the recurrent
// kernel consumes: frag id G = t*8192 + wg*256 + kt*64 + ln (16 B each).
// Lane(ln): lm=ln&15 (batch row), lq=ln>>4; frag = x[b0+lm][t][n*128+kt*32+lq*8 ..+8].
__global__ void x_to_frag(const float* __restrict__ x, int4* __restrict__ xf) {
    const unsigned G = blockIdx.x * 256 + threadIdx.x;   // < 4194304
    const int ln = G & 63;
    const int kt = (G >> 6) & 3;
    const int wg = (G >> 8) & 31;
    const int t  = G >> 13;
    const int lm = ln & 15, lq = ln >> 4;
    const int n  = wg >> 1;
    const int b0 = (wg & 1) * 16;
    const float* src = x + (size_t)(b0 + lm) * (TSZ * XROW) + (size_t)t * XROW
                         + n * ISZ + kt * 32 + lq * 8;
    float4 a = *(const float4*)src;
    float4 b = *(const float4*)(src + 4);
    s16x8 f;
    f[0] = (short)f2bf(a.x); f[1] = (short)f2bf(a.y);
    f[2] = (short)f2bf(a.z); f[3] = (short)f2bf(a.w);
    f[4] = (short)f2bf(b.x); f[5] = (short)f2bf(b.y);
    f[6] = (short)f2bf(b.z); f[7] = (short)f2bf(b.w);
    xf[G] = __builtin_bit_cast(int4, f);
}

// One workgroup = (n, batch-half of 16). 8 waves; wave w owns hidden units
// [16w,16w+16) x all 4 gates. Weights PRESCALED by -log2e (i,f,o) / -2log2e (g)
// so gate pre-activations are exp2-ready (bare v_exp_f32, one-sided clamp).
// h round-trips through LDS bf16 (the only barrier dependency). x arrives as
// pre-packed A-fragments straight from global (PRE=1), prefetched 1 step ahead.
template <int PRE>
__global__ __launch_bounds__(512, 2) void widelstm_fused(
    const float* __restrict__ x, const int4* __restrict__ xf,
    const float* __restrict__ Wih, const float* __restrict__ Whh,
    const float* __restrict__ bih, const float* __restrict__ bhh,
    float* __restrict__ out)
{
    __shared__ __align__(16) unsigned short xbuf[2][16][136];   // PRE=0 only
    __shared__ __align__(16) unsigned short hbuf[2][16][136];

    const int tid = threadIdx.x;
    const int wv  = tid >> 6;        // wave 0..7 -> hid chunk
    const int ln  = tid & 63;
    const int lm  = ln & 15;         // A-row (m) / C-col
    const int lq  = ln >> 4;         // quad
    const int n    = blockIdx.x >> 1;
    const int half = blockIdx.x & 1;
    const int b0   = half * 16;

    // ---- Load weight B-fragments (once), prescaled per gate.
    const float gsc[4] = {-LOG2E, -LOG2E, -2.f * LOG2E, -LOG2E};   // i,f,g,o
    s16x8 wih[4][4], whh[4][4];
    f32x4 biasv[4];   // persistent broadcast bias (MFMA C-in)
    #pragma unroll
    for (int g = 0; g < 4; ++g) {
        const int col = g * 128 + wv * 16 + lm;
        const float s = gsc[g];
        const float bb = (bih[n * G4H + col] + bhh[n * G4H + col]) * s;
        biasv[g] = (f32x4){bb, bb, bb, bb};
        #pragma unroll
        for (int kt = 0; kt < 4; ++kt) {
            const float* pi = Wih + ((size_t)n * G4H + col) * ISZ + kt * 32 + lq * 8;
            const float* ph = Whh + ((size_t)n * G4H + col) * HSZ + kt * 32 + lq * 8;
            s16x8 a, b;
            #pragma unroll
            for (int j = 0; j < 8; ++j) {
                a[j] = (short)f2bf(pi[j] * s);
                b[j] = (short)f2bf(ph[j] * s);
            }
            wih[g][kt] = a;
            whh[g][kt] = b;
        }
    }

    // zero hbuf[0] (h(-1) = 0); visible after step-0's barrier
    for (int i = tid; i < 16 * 136; i += 512)
        ((unsigned short*)hbuf[0])[i] = 0;

    // ---- x sources
    const int sr = tid >> 5;
    const int sc = (tid & 31) * 4;
    const float* xrow = x + (size_t)(b0 + sr) * TSZ * XROW + n * ISZ + sc;   // PRE=0
    const int4* xfb = xf + (size_t)blockIdx.x * 256 + ln;   // + t*8192 + kt*64 (PRE=1)

    float4 xr;                   // PRE=0 prefetch
    s16x8 xra, xrb, xrc, xrd;    // PRE=1 prefetched frags (for t+1)
    f32x4 xacc[4];

    // ---- prologue: xacc(0) = bias + Wih*x(0); prefetch x(1)
    if constexpr (PRE) {
        s16x8 c0 = __builtin_bit_cast(s16x8, xfb[0]);
        s16x8 c1 = __builtin_bit_cast(s16x8, xfb[64]);
        s16x8 c2 = __builtin_bit_cast(s16x8, xfb[128]);
        s16x8 c3 = __builtin_bit_cast(s16x8, xfb[192]);
        #pragma unroll
        for (int g = 0; g < 4; ++g)
            xacc[g] = __builtin_amdgcn_mfma_f32_16x16x32_bf16(c0, wih[g][0], biasv[g], 0, 0, 0);
        #pragma unroll
        for (int g = 0; g < 4; ++g)
            xacc[g] = __builtin_amdgcn_mfma_f32_16x16x32_bf16(c1, wih[g][1], xacc[g], 0, 0, 0);
        #pragma unroll
        for (int g = 0; g < 4; ++g)
            xacc[g] = __builtin_amdgcn_mfma_f32_16x16x32_bf16(c2, wih[g][2], xacc[g], 0, 0, 0);
        #pragma unroll
        for (int g = 0; g < 4; ++g)
            xacc[g] = __builtin_amdgcn_mfma_f32_16x16x32_bf16(c3, wih[g][3], xacc[g], 0, 0, 0);
        xra = __builtin_bit_cast(s16x8, xfb[8192]);
        xrb = __builtin_bit_cast(s16x8, xfb[8192 + 64]);
        xrc = __builtin_bit_cast(s16x8, xfb[8192 + 128]);
        xrd = __builtin_bit_cast(s16x8, xfb[8192 + 192]);
    } else {
        xr = *(const float4*)(xrow);
        unsigned int lo = (unsigned int)f2bf(xr.x) | ((unsigned int)f2bf(xr.y) << 16);
        unsigned int hi = (unsigned int)f2bf(xr.z) | ((unsigned int)f2bf(xr.w) << 16);
        *(uint2*)&xbuf[0][sr][sc] = make_uint2(lo, hi);
        barrier_lgkm();
        #pragma unroll
        for (int kt = 0; kt < 4; ++kt) {
            s16x8 axk = *(const s16x8*)&xbuf[0][lm][kt * 32 + lq * 8];
            #pragma unroll
            for (int g = 0; g < 4; ++g)
                xacc[g] = __builtin_amdgcn_mfma_f32_16x16x32_bf16(
                    axk, wih[g][kt], kt == 0 ? biasv[g] : xacc[g], 0, 0, 0);
        }
        xr = *(const float4*)(xrow + (size_t)XROW);
    }

    float cprev[4] = {0.f, 0.f, 0.f, 0.f};
    float hlast[4] = {0.f, 0.f, 0.f, 0.f};
    const int ocol = n * HSZ + wv * 16 + lm;

    float* po0 = out + (size_t)(b0 + lq * 4 + 0) * TSZ * OROW + ocol;
    float* po1 = out + (size_t)(b0 + lq * 4 + 1) * TSZ * OROW + ocol;
    float* po2 = out + (size_t)(b0 + lq * 4 + 2) * TSZ * OROW + ocol;
    float* po3 = out + (size_t)(b0 + lq * 4 + 3) * TSZ * OROW + ocol;

#define LSTM_STEP(T_, CUR_, NXT_)                                                          \
    {                                                                                      \
        const int t_ = (T_);                                                               \
        if constexpr (!PRE) {                                                              \
            if (t_ + 1 < TSZ) {                                                            \
                unsigned int lo = (unsigned int)f2bf(xr.x) | ((unsigned int)f2bf(xr.y) << 16); \
                unsigned int hi = (unsigned int)f2bf(xr.z) | ((unsigned int)f2bf(xr.w) << 16); \
                *(uint2*)&xbuf[NXT_][sr][sc] = make_uint2(lo, hi);                         \
            }                                                                              \
        }                                                                                  \
        barrier_lgkm();  /* h(t-1) writes (+ PRE=0 x staging) now visible */               \
        s16x8 ah0 = *(const s16x8*)&hbuf[CUR_][lm][0 * 32 + lq * 8];                       \
        s16x8 ah1 = *(const s16x8*)&hbuf[CUR_][lm][1 * 32 + lq * 8];                       \
        s16x8 ah2 = *(const s16x8*)&hbuf[CUR_][lm][2 * 32 + lq * 8];                       \
        s16x8 ah3 = *(const s16x8*)&hbuf[CUR_][lm][3 * 32 + lq * 8];                       \
        if constexpr (!PRE) {                                                              \
            if (t_ + 2 < TSZ) xr = *(const float4*)(xrow + (size_t)(t_ + 2) * XROW);       \
        }                                                                                  \
        f32x4 hacc[4];                                                                     \
        _Pragma("unroll")                                                                  \
        for (int g = 0; g < 4; ++g)                                                        \
            hacc[g] = __builtin_amdgcn_mfma_f32_16x16x32_bf16(ah0, whh[g][0], xacc[g], 0, 0, 0); \
        _Pragma("unroll")                                                                  \
        for (int g = 0; g < 4; ++g)                                                        \
            hacc[g] = __builtin_amdgcn_mfma_f32_16x16x32_bf16(ah1, whh[g][1], hacc[g], 0, 0, 0); \
        _Pragma("unroll")                                                                  \
        for (int g = 0; g < 4; ++g)                                                        \
            hacc[g] = __builtin_amdgcn_mfma_f32_16x16x32_bf16(ah2, whh[g][2], hacc[g], 0, 0, 0); \
        _Pragma("unroll")                                                                  \
        for (int g = 0; g < 4; ++g)                                                        \
            hacc[g] = __builtin_amdgcn_mfma_f32_16x16x32_bf16(ah3, whh[g][3], hacc[g], 0, 0, 0); \
        if (t_ + 1 < TSZ) { /* x-projection for t+1: off the critical path */              \
            if constexpr (PRE) {                                                           \
                _Pragma("unroll")                                                          \
                for (int g = 0; g < 4; ++g)                                                \
                    xacc[g] = __builtin_amdgcn_mfma_f32_16x16x32_bf16(xra, wih[g][0], biasv[g], 0, 0, 0); \
                _Pragma("unroll")                                                          \
                for (int g = 0; g < 4; ++g)                                                \
                    xacc[g] = __builtin_amdgcn_mfma_f32_16x16x32_bf16(xrb, wih[g][1], xacc[g], 0, 0, 0); \
                _Pragma("unroll")                                                          \
                for (int g = 0; g < 4; ++g)                                                \
                    xacc[g] = __builtin_amdgcn_mfma_f32_16x16x32_bf16(xrc, wih[g][2], xacc[g], 0, 0, 0); \
                _Pragma("unroll")                                                          \
                for (int g = 0; g < 4; ++g)                                                \
                    xacc[g] = __builtin_amdgcn_mfma_f32_16x16x32_bf16(xrd, wih[g][3], xacc[g], 0, 0, 0); \
                if (t_ + 2 < TSZ) { /* prefetch frags for t+2 */                           \
                    const int4* p = xfb + (size_t)(t_ + 2) * 8192;                         \
                    xra = __builtin_bit_cast(s16x8, p[0]);                                 \
                    xrb = __builtin_bit_cast(s16x8, p[64]);                                \
                    xrc = __builtin_bit_cast(s16x8, p[128]);                               \
                    xrd = __builtin_bit_cast(s16x8, p[192]);                               \
                }                                                                          \
            } else {                                                                       \
                _Pragma("unroll")                                                          \
                for (int kt = 0; kt < 4; ++kt) {                                           \
                    s16x8 axk = *(const s16x8*)&xbuf[NXT_][lm][kt * 32 + lq * 8];          \
                    _Pragma("unroll")                                                      \
                    for (int g = 0; g < 4; ++g)                                            \
                        xacc[g] = __builtin_amdgcn_mfma_f32_16x16x32_bf16(                 \
                            axk, wih[g][kt], kt == 0 ? biasv[g] : xacc[g], 0, 0, 0);       \
                }                                                                          \
            }                                                                              \
        }                                                                                  \
        /* epilogue: pre-activations already scaled; exp2-direct.                          \
           sig(i)*tanh(g) = (1-eg)*rcp((1+ei)(1+eg));                                      \
           sig(o)*tanh(c) = (1-ec)*rcp((1+eo)(1+ec)). 5 exp2 + 3 rcp per elem. */          \
        _Pragma("unroll")                                                                  \
        for (int r = 0; r < 4; ++r) {                                                      \
            float ei = fexp2(hacc[0][r]);                                                  \
            float ef = fexp2(hacc[1][r]);                                                  \
            float eg = fexp2(fminf(hacc[2][r], 80.f));                                     \
            float eo = fexp2(hacc[3][r]);                                                  \
            float fv = __builtin_amdgcn_rcpf(1.f + ef);                                    \
            float ig = (1.f - eg) * __builtin_amdgcn_rcpf((1.f + ei) * (1.f + eg));        \
            float c  = fv * cprev[r] + ig;                                                 \
            cprev[r] = c;                                                                  \
            float ec = fexp2(fminf(c * (-2.f * LOG2E), 80.f));                             \
            float hv = (1.f - ec) * __builtin_amdgcn_rcpf((1.f + eo) * (1.f + ec));        \
            hlast[r] = hv;                                                                 \
            hbuf[NXT_][lq * 4 + r][wv * 16 + lm] = f2bf(hv);                               \
            if (r == 0) { *po0 = hv; po0 += OROW; }                                        \
            if (r == 1) { *po1 = hv; po1 += OROW; }                                        \
            if (r == 2) { *po2 = hv; po2 += OROW; }                                        \
            if (r == 3) { *po3 = hv; po3 += OROW; }                                        \
        }                                                                                  \
    }

    for (int t = 0; t < TSZ; t += 2) {
        LSTM_STEP(t, 0, 1);
        LSTM_STEP(t + 1, 1, 0);
    }
#undef LSTM_STEP

    // finals: h_n, c_n  [1, B, N*H] each
    const size_t hn_off = (size_t)BSZ * TSZ * OROW;
    const size_t cn_off = hn_off + (size_t)BSZ * OROW;
    #pragma unroll
    for (int r = 0; r < 4; ++r) {
        const int row = lq * 4 + r;
        const size_t idx = (size_t)(b0 + row) * OROW + ocol;
        out[hn_off + idx] = hlast[r];
        out[cn_off + idx] = cprev[r];
    }
}

extern "C" void kernel_launch(void* const* d_in, const int* in_sizes, int n_in,
                              void* d_out, int out_size, void* d_ws, size_t ws_size,
                              hipStream_t stream) {
    const float* x   = (const float*)d_in[0];
    const float* Wih = (const float*)d_in[1];
    const float* Whh = (const float*)d_in[2];
    const float* bih = (const float*)d_in[3];
    const float* bhh = (const float*)d_in[4];
    float* out = (float*)d_out;

    const size_t need = (size_t)TSZ * 32 * 4 * 64 * 16;   // 64 MiB
    if (d_ws != nullptr && ws_size >= need) {
        int4* xfrag = (int4*)d_ws;
        x_to_frag<<<dim3(16384), dim3(256), 0, stream>>>(x, xfrag);
        widelstm_fused<1><<<dim3(32), dim3(512), 0, stream>>>(x, xfrag, Wih, Whh, bih, bhh, out);
    } else {
        widelstm_fused<0><<<dim3(32), dim3(512), 0, stream>>>(x, nullptr, Wih, Whh, bih, bhh, out);
    }
}